// Round 6
// baseline (631.898 us; speedup 1.0000x reference)
//
#include <hip/hip_runtime.h>

#define NB    16
#define NCIN  16
#define NCOUT 64
#define NT    50
#define NH    32
#define NW    32
#define NHW   1024
#define WROW  432   // CIN * 27

// ---- workspace layout (bytes) ----
// conv_x  : float[16*50*1024*64]           @ 0            (209,715,200 B)  layout [(b*NT+t)*NHW+px][cout]
// dmat    : float[4096]                    @ 209,715,200  (16,384 B)
// inv_norm: float[64]                      @ 209,731,584  (256 B)
// bits    : u64[16384*50]                  @ 209,731,840  (6,553,600 B)    layout [(b*NT+t)*NHW+px]
// cnt     : int[50]                        @ 216,285,440  (200 B)

// ---------------------------------------------------------------
// Gram matrix d = w . w^T  (rows of length 432), inv_norm
// ---------------------------------------------------------------
__global__ __launch_bounds__(64) void gram_kernel(const float* __restrict__ w,
                                                  float* __restrict__ dmat,
                                                  float* __restrict__ invn) {
    const int c = blockIdx.x;   // 0..63
    const int e = threadIdx.x;  // 0..63
    const float* wc = w + c * WROW;
    const float* we = w + e * WROW;
    float acc = 0.f;
    for (int k = 0; k < WROW; ++k) acc = fmaf(wc[k], we[k], acc);
    dmat[c * 64 + e] = acc;
    if (c == e) invn[e] = 1.0f / (acc + 1e-8f);
}

// ---------------------------------------------------------------
// Direct 3D conv, fp32. Block = (og, t, b); thread = 1x4 strip x 8 oc.
// Grid (og fastest): the 8 og-blocks of one (b,t) slab are concurrent and
// t-adjacent blocks share planes in L2 (measured 206 MB fetch vs 604 MB for
// og-slowest).
// DOUBLE-BUFFERED slab: per c-iter {ds_write c+1 -> slab[cur^1], issue
// global loads c+2, MAC slab[cur], ONE barrier, flip}. ds_writes drain
// under the 864-FMA MAC instead of sitting between two barriers.
// Invalid t-edge planes are never written and stay zero (both buffers
// zero-initialized once).
// Per-accumulator FMA order (c -> kt -> kh -> kw) identical to the verified
// kernel -> bit-identical conv output.
// ---------------------------------------------------------------
#define XROW 35
#define XPLANE (34 * XROW)   // 1190
#define XTOT (3 * XPLANE)    // 3570

__global__ __launch_bounds__(256) void conv_kernel(const float* __restrict__ x,
                                                   const float* __restrict__ w,
                                                   float* __restrict__ convo) {
    const int og  = blockIdx.x;   // 0..7
    const int t   = blockIdx.y;   // 0..49
    const int b   = blockIdx.z;   // 0..15
    const int tid = threadIdx.x;

    __shared__ float xt[2][XTOT];         // two padded 3-plane slabs, pads stay 0
    __shared__ float wsm[NCIN * 27 * 8];  // [c][kidx][oi]  (3456 floats)

    bool pv[3];
    pv[0] = (t >= 1);
    pv[1] = true;
    pv[2] = (t <= NT - 2);

    const float4* x4 = (const float4*)x;
    // float4 index for (c,kt): ((b*16+c)*50 + (t-1+kt))*256 + tid
    const long gb = ((long)b * NCIN * NT + (t - 1)) * 256 + tid;

    // issue c=0 loads first so they drain under the init/staging work
    float4 pf[3];
#pragma unroll
    for (int kt = 0; kt < 3; ++kt)
        if (pv[kt]) pf[kt] = x4[gb + kt * 256];

    // zero-init both slabs (pads + invalid t-edge planes remain zero forever)
    for (int i = tid; i < XTOT; i += 256) { xt[0][i] = 0.f; xt[1][i] = 0.f; }

    // stage weights re-laid-out as [c][kidx][oi] for broadcast b128 reads
    for (int i = tid; i < NCIN * 27 * 8; i += 256) {
        int oi = i & 7;
        int r  = i >> 3;                  // c*27 + kidx
        wsm[i] = w[(og * 8 + oi) * WROW + r];
    }

    const int h  = tid >> 3;              // row 0..31
    const int w0 = (tid & 7) << 2;        // col 0,4,...,28
    const int lbase = (h + 1) * XROW + (w0 + 1);   // interior LDS cell

    __syncthreads();   // zero-init done before any interior write

    // write c=0 into slab 0, then issue c=1 loads
#pragma unroll
    for (int kt = 0; kt < 3; ++kt) {
        if (pv[kt]) {
            float* d = &xt[0][kt * XPLANE + lbase];
            d[0] = pf[kt].x; d[1] = pf[kt].y; d[2] = pf[kt].z; d[3] = pf[kt].w;
        }
    }
#pragma unroll
    for (int kt = 0; kt < 3; ++kt)
        if (pv[kt]) pf[kt] = x4[gb + (long)(NT * 256) + kt * 256];

    float acc[8][4];
#pragma unroll
    for (int oi = 0; oi < 8; ++oi)
#pragma unroll
        for (int p = 0; p < 4; ++p) acc[oi][p] = 0.f;

    __syncthreads();   // slab 0 + weights visible

    int cur = 0;
#pragma unroll 1
    for (int c = 0; c < NCIN; ++c) {
        // stage channel c+1 into the other slab; prefetch c+2 from global
        if (c + 1 < NCIN) {
#pragma unroll
            for (int kt = 0; kt < 3; ++kt) {
                if (pv[kt]) {
                    float* d = &xt[cur ^ 1][kt * XPLANE + lbase];
                    d[0] = pf[kt].x; d[1] = pf[kt].y; d[2] = pf[kt].z; d[3] = pf[kt].w;
                }
            }
            if (c + 2 < NCIN) {
                const long g = gb + (long)(c + 2) * (NT * 256);
#pragma unroll
                for (int kt = 0; kt < 3; ++kt)
                    if (pv[kt]) pf[kt] = x4[g + kt * 256];
            }
        }

        // MAC from slab[cur] (channel c)
        const float* slab = &xt[cur][0];
        const float* wc = &wsm[c * 216];
#pragma unroll
        for (int kt = 0; kt < 3; ++kt) {
#pragma unroll
            for (int kh = 0; kh < 3; ++kh) {
                const float* xp = &slab[kt * XPLANE + (h + kh) * XROW + w0];
                float xv[6];
#pragma unroll
                for (int j = 0; j < 6; ++j) xv[j] = xp[j];
#pragma unroll
                for (int kw = 0; kw < 3; ++kw) {
                    const float4 wa = *(const float4*)&wc[(kt * 9 + kh * 3 + kw) * 8];
                    const float4 wb = *(const float4*)&wc[(kt * 9 + kh * 3 + kw) * 8 + 4];
#pragma unroll
                    for (int p = 0; p < 4; ++p) {
                        acc[0][p] = fmaf(wa.x, xv[kw + p], acc[0][p]);
                        acc[1][p] = fmaf(wa.y, xv[kw + p], acc[1][p]);
                        acc[2][p] = fmaf(wa.z, xv[kw + p], acc[2][p]);
                        acc[3][p] = fmaf(wa.w, xv[kw + p], acc[3][p]);
                        acc[4][p] = fmaf(wb.x, xv[kw + p], acc[4][p]);
                        acc[5][p] = fmaf(wb.y, xv[kw + p], acc[5][p]);
                        acc[6][p] = fmaf(wb.z, xv[kw + p], acc[6][p]);
                        acc[7][p] = fmaf(wb.w, xv[kw + p], acc[7][p]);
                    }
                }
            }
        }

        __syncthreads();   // c+1 writes complete; everyone done reading slab[cur]
        cur ^= 1;
    }

    const size_t pxbase = ((size_t)(b * NT + t) * NHW + h * NW + w0) * NCOUT + og * 8;
#pragma unroll
    for (int p = 0; p < 4; ++p) {
        float4 v0 = make_float4(acc[0][p], acc[1][p], acc[2][p], acc[3][p]);
        float4 v1 = make_float4(acc[4][p], acc[5][p], acc[6][p], acc[7][p]);
        float4* dst = (float4*)(convo + pxbase + (size_t)p * NCOUT);
        dst[0] = v0;
        dst[1] = v1;
    }
}

// ---------------------------------------------------------------
// Temporal scan: one wave per pixel, lane = output channel.
// No LDS, no atomics. Sparse spk@d / spk@v served from L2 (spikes are
// ~3.5-sigma rare); conv value for t+1 prefetched 1 deep.
// ---------------------------------------------------------------
__global__ __launch_bounds__(256) void scan_kernel(const float* __restrict__ convo,
                                                   const float* __restrict__ vmatg,
                                                   const float* __restrict__ betap,
                                                   const float* __restrict__ bp,
                                                   const float* __restrict__ dmatg,
                                                   const float* __restrict__ invng,
                                                   unsigned long long* __restrict__ bits) {
    const int tid  = threadIdx.x;
    const int wv   = (blockIdx.x << 2) + (tid >> 6);  // pixel id 0..16383
    const int lane = tid & 63;
    const int b  = wv >> 10;
    const int px = wv & 1023;

    const float beta = betap[0];
    const float omb  = 1.0f - beta;
    const float bb   = bp[lane];
    const float inv  = invng[lane];

    float mem = 0.f;
    unsigned long long mask = 0ull;   // spk(t-1), bit c = channel c

    const float* cbase = convo + ((size_t)(b * NT) * NHW + px) * NCOUT + lane;
    const size_t bitbase = (size_t)(b * NT) * NHW + px;

    float cv_next = cbase[0];
    for (int t = 0; t < NT; ++t) {
        float cv = cv_next;
        if (t + 1 < NT) cv_next = cbase[(size_t)(t + 1) * NHW * NCOUT];

        float rst = 0.f, vin = 0.f;
        unsigned long long m = mask;
        while (m) {                        // ascending c: exact vs dense in-order sum
            int c = __builtin_ctzll(m);
            m &= m - 1;
            rst += dmatg[(c << 6) + lane];
            vin += vmatg[(c << 6) + lane];
        }
        float inp = cv + vin;
        mem  = fmaf(mem - rst, beta, inp * omb);
        float mthr = fmaf(mem, inv, -bb);
        int s = mthr > 0.0f;
        mask = __ballot(s);
        if (lane == 0) bits[bitbase + (size_t)t * NHW] = mask;
    }
}

// ---------------------------------------------------------------
// Per-t spike counts from the packed bitmasks (no atomics anywhere)
// ---------------------------------------------------------------
__global__ __launch_bounds__(256) void count_kernel(const unsigned long long* __restrict__ bits,
                                                    int* __restrict__ cnt) {
    const int t = blockIdx.x;   // 0..49
    int sum = 0;
    for (int i = threadIdx.x; i < NB * NHW; i += 256) {
        int b  = i >> 10;
        int px = i & 1023;
        sum += __popcll(bits[((size_t)(b * NT + t) << 10) + px]);
    }
    __shared__ int sh[4];
#pragma unroll
    for (int off = 32; off > 0; off >>= 1) sum += __shfl_down(sum, off);
    if ((threadIdx.x & 63) == 0) sh[threadIdx.x >> 6] = sum;
    __syncthreads();
    if (threadIdx.x == 0) cnt[t] = sh[0] + sh[1] + sh[2] + sh[3];
}

// ---------------------------------------------------------------
// Unpack bitmasks -> fp32 spk_rec in (B, COUT, T, H, W) order
// ---------------------------------------------------------------
__global__ __launch_bounds__(256) void unpack_kernel(const unsigned long long* __restrict__ bits,
                                                     float* __restrict__ out) {
    const long long total4 = 13107200;  // 52,428,800 / 4
    const long long stride = (long long)gridDim.x * blockDim.x;
    for (long long i4 = (long long)blockIdx.x * 256 + threadIdx.x; i4 < total4; i4 += stride) {
        long long flat = i4 << 2;
        int hw = (int)(flat & 1023);
        long long r = flat >> 10;        // (b*64+o)*50 + t
        int t = (int)(r % 50);
        long long r2 = r / 50;           // b*64 + o
        int o = (int)(r2 & 63);
        int b = (int)(r2 >> 6);
        const unsigned long long* bq = bits + ((long long)(b * NT + t) << 10) + hw;
        float4 v;
        v.x = (float)((bq[0] >> o) & 1ull);
        v.y = (float)((bq[1] >> o) & 1ull);
        v.z = (float)((bq[2] >> o) & 1ull);
        v.w = (float)((bq[3] >> o) & 1ull);
        *(float4*)(out + flat) = v;
    }
}

// ---------------------------------------------------------------
// loss = 0.5 * sum(spk)/52428800 (spk^2 == spk), spread = max_t cnt[t]/1048576
// ---------------------------------------------------------------
__global__ __launch_bounds__(64) void finalize_kernel(const int* __restrict__ cnt,
                                                      float* __restrict__ out) {
    const int lane = threadIdx.x;
    int c = (lane < NT) ? cnt[lane] : 0;
    int tot = c, mx = c;
#pragma unroll
    for (int off = 32; off > 0; off >>= 1) {
        tot += __shfl_down(tot, off);
        mx = max(mx, __shfl_down(mx, off));
    }
    if (lane == 0) {
        out[52428800] = 0.5f * (float)tot / 52428800.0f;
        out[52428801] = (float)mx / 1048576.0f;
    }
}

extern "C" void kernel_launch(void* const* d_in, const int* in_sizes, int n_in,
                              void* d_out, int out_size, void* d_ws, size_t ws_size,
                              hipStream_t stream) {
    const float* x    = (const float*)d_in[0];
    const float* w    = (const float*)d_in[1];
    const float* v    = (const float*)d_in[2];
    const float* beta = (const float*)d_in[3];
    const float* b    = (const float*)d_in[4];
    // sigma (d_in[5]) only affects the backward pass — unused here.
    float* out = (float*)d_out;

    char* ws = (char*)d_ws;
    float* convo              = (float*)(ws);
    float* dmat               = (float*)(ws + 209715200);
    float* invn               = (float*)(ws + 209715200 + 16384);
    unsigned long long* bits  = (unsigned long long*)(ws + 209731840);
    int* cnt                  = (int*)(ws + 216285440);

    gram_kernel<<<64, 64, 0, stream>>>(w, dmat, invn);
    conv_kernel<<<dim3(8, NT, NB), 256, 0, stream>>>(x, w, convo);
    scan_kernel<<<4096, 256, 0, stream>>>(convo, v, beta, b, dmat, invn, bits);
    count_kernel<<<NT, 256, 0, stream>>>(bits, cnt);
    unpack_kernel<<<4096, 256, 0, stream>>>(bits, out);
    finalize_kernel<<<1, 64, 0, stream>>>(cnt, out);
}

// Round 7
// 545.281 us; speedup vs baseline: 1.1588x; 1.1588x over previous
//
#include <hip/hip_runtime.h>

#define NB    16
#define NCIN  16
#define NCOUT 64
#define NT    50
#define NH    32
#define NW    32
#define NHW   1024
#define WROW  432   // CIN * 27

// ---- workspace layout (bytes) ----
// conv_x  : float[16*50*1024*64]           @ 0            (209,715,200 B)  layout [(b*NT+t)*NHW+px][cout]
// dmat    : float[4096]                    @ 209,715,200  (16,384 B)
// inv_norm: float[64]                      @ 209,731,584  (256 B)
// bits    : u64[16384*50]                  @ 209,731,840  (6,553,600 B)    layout [(b*NT+t)*NHW+px]
// cnt     : int[50]                        @ 216,285,440  (200 B)
// wT      : float[432*64]                  @ 216,285,696  (110,592 B)      layout [c*27+ki][o]

// ---------------------------------------------------------------
// Gram matrix d = w . w^T  (rows of length 432), inv_norm
// ---------------------------------------------------------------
__global__ __launch_bounds__(64) void gram_kernel(const float* __restrict__ w,
                                                  float* __restrict__ dmat,
                                                  float* __restrict__ invn) {
    const int c = blockIdx.x;   // 0..63
    const int e = threadIdx.x;  // 0..63
    const float* wc = w + c * WROW;
    const float* we = w + e * WROW;
    float acc = 0.f;
    for (int k = 0; k < WROW; ++k) acc = fmaf(wc[k], we[k], acc);
    dmat[c * 64 + e] = acc;
    if (c == e) invn[e] = 1.0f / (acc + 1e-8f);
}

// ---------------------------------------------------------------
// Weight transpose: wT[r][o] = w[o][r]  (r = c*27+ki, 432x64)
// Gives 8 consecutive uniform floats per (c,ki,og) -> s_load_dwordx8 in conv.
// ---------------------------------------------------------------
__global__ __launch_bounds__(256) void wtrans_kernel(const float* __restrict__ w,
                                                     float* __restrict__ wT) {
    int idx = blockIdx.x * 256 + threadIdx.x;   // 0..27647
    int r = idx >> 6;
    int o = idx & 63;
    wT[idx] = w[o * WROW + r];
}

// ---------------------------------------------------------------
// Direct 3D conv, fp32. Block = (og, t, b); thread = 1x4 strip x 8 oc.
// og fastest: the 8 og-blocks of one (b,t) slab are concurrent -> slab shared
// in L2 (measured 216 MB fetch vs 604 MB og-slowest).
// Single LDS slab (14.7 KB, no weight LDS) -> high occupancy (round-6 lesson:
// occupancy > barrier-thinning).
// Weights via wT: block-uniform addresses -> scalar loads (SGPR), FMA takes
// the weight as the one allowed SGPR operand. No weight ds_reads at all.
// XROW=36 makes xv read base 16B-aligned -> float4+float2 LDS reads.
// Per-accumulator FMA order (c -> kt -> kh -> kw) identical to the verified
// kernel -> bit-identical conv output.
// ---------------------------------------------------------------
#define XROW 36
#define XPLANE (34 * XROW)   // 1224
#define XTOT (3 * XPLANE)    // 3672

__global__ __launch_bounds__(256) void conv_kernel(const float* __restrict__ x,
                                                   const float* __restrict__ wT,
                                                   float* __restrict__ convo) {
    const int og  = blockIdx.x;   // 0..7
    const int t   = blockIdx.y;   // 0..49
    const int b   = blockIdx.z;   // 0..15
    const int tid = threadIdx.x;

    __shared__ __align__(16) float xt[XTOT];   // padded 3-plane slab, pads stay 0

    bool pv[3];
    pv[0] = (t >= 1);
    pv[1] = true;
    pv[2] = (t <= NT - 2);

    const float4* x4 = (const float4*)x;
    // float4 index for (c,kt): ((b*16+c)*50 + (t-1+kt))*256 + tid
    const long gb = ((long)b * NCIN * NT + (t - 1)) * 256 + tid;

    // issue c=0 loads first so they drain under the zero-init
    float4 pf[3];
#pragma unroll
    for (int kt = 0; kt < 3; ++kt)
        if (pv[kt]) pf[kt] = x4[gb + kt * 256];

    // zero-init slab (pads + invalid t-edge planes remain zero forever)
    for (int i = tid; i < XTOT; i += 256) xt[i] = 0.f;

    const int h  = tid >> 3;              // row 0..31
    const int w0 = (tid & 7) << 2;        // col 0,4,...,28
    const int lbase = (h + 1) * XROW + (w0 + 1);   // interior LDS cell

    const float* wtg = wT + og * 8;       // + (c*27+ki)*64, block-uniform

    float acc[8][4];
#pragma unroll
    for (int oi = 0; oi < 8; ++oi)
#pragma unroll
        for (int p = 0; p < 4; ++p) acc[oi][p] = 0.f;

    __syncthreads();   // zero-init complete before interior writes

#pragma unroll 1
    for (int c = 0; c < NCIN; ++c) {
        // write channel c (in pf) into slab; issue c+1 global loads
#pragma unroll
        for (int kt = 0; kt < 3; ++kt) {
            if (pv[kt]) {
                float* d = &xt[kt * XPLANE + lbase];
                d[0] = pf[kt].x; d[1] = pf[kt].y; d[2] = pf[kt].z; d[3] = pf[kt].w;
            }
        }
        if (c + 1 < NCIN) {
            const long g = gb + (long)(c + 1) * (NT * 256);
#pragma unroll
            for (int kt = 0; kt < 3; ++kt)
                if (pv[kt]) pf[kt] = x4[g + kt * 256];
        }
        __syncthreads();   // slab (channel c) visible

        // MAC channel c
#pragma unroll
        for (int kt = 0; kt < 3; ++kt) {
#pragma unroll
            for (int kh = 0; kh < 3; ++kh) {
                const float* xp = &xt[kt * XPLANE + (h + kh) * XROW + w0];  // 16B-aligned
                const float4 xa = *(const float4*)xp;
                const float2 xb = *(const float2*)(xp + 4);
                const float xv[6] = {xa.x, xa.y, xa.z, xa.w, xb.x, xb.y};
#pragma unroll
                for (int kw = 0; kw < 3; ++kw) {
                    const float* wrow = wtg + (c * 27 + kt * 9 + kh * 3 + kw) * 64; // uniform
#pragma unroll
                    for (int oi = 0; oi < 8; ++oi) {
                        const float wv = wrow[oi];   // scalar (SGPR) load
#pragma unroll
                        for (int p = 0; p < 4; ++p)
                            acc[oi][p] = fmaf(wv, xv[kw + p], acc[oi][p]);
                    }
                }
            }
        }

        __syncthreads();   // MAC done before slab overwrite (next c)
    }

    const size_t pxbase = ((size_t)(b * NT + t) * NHW + h * NW + w0) * NCOUT + og * 8;
#pragma unroll
    for (int p = 0; p < 4; ++p) {
        float4 v0 = make_float4(acc[0][p], acc[1][p], acc[2][p], acc[3][p]);
        float4 v1 = make_float4(acc[4][p], acc[5][p], acc[6][p], acc[7][p]);
        float4* dst = (float4*)(convo + pxbase + (size_t)p * NCOUT);
        dst[0] = v0;
        dst[1] = v1;
    }
}

// ---------------------------------------------------------------
// Temporal scan: one wave per pixel, lane = output channel.
// No LDS, no atomics. Sparse spk@d / spk@v served from L2 (spikes are
// ~3.5-sigma rare); conv value for t+1 prefetched 1 deep.
// ---------------------------------------------------------------
__global__ __launch_bounds__(256) void scan_kernel(const float* __restrict__ convo,
                                                   const float* __restrict__ vmatg,
                                                   const float* __restrict__ betap,
                                                   const float* __restrict__ bp,
                                                   const float* __restrict__ dmatg,
                                                   const float* __restrict__ invng,
                                                   unsigned long long* __restrict__ bits) {
    const int tid  = threadIdx.x;
    const int wv   = (blockIdx.x << 2) + (tid >> 6);  // pixel id 0..16383
    const int lane = tid & 63;
    const int b  = wv >> 10;
    const int px = wv & 1023;

    const float beta = betap[0];
    const float omb  = 1.0f - beta;
    const float bb   = bp[lane];
    const float inv  = invng[lane];

    float mem = 0.f;
    unsigned long long mask = 0ull;   // spk(t-1), bit c = channel c

    const float* cbase = convo + ((size_t)(b * NT) * NHW + px) * NCOUT + lane;
    const size_t bitbase = (size_t)(b * NT) * NHW + px;

    float cv_next = cbase[0];
    for (int t = 0; t < NT; ++t) {
        float cv = cv_next;
        if (t + 1 < NT) cv_next = cbase[(size_t)(t + 1) * NHW * NCOUT];

        float rst = 0.f, vin = 0.f;
        unsigned long long m = mask;
        while (m) {                        // ascending c: exact vs dense in-order sum
            int c = __builtin_ctzll(m);
            m &= m - 1;
            rst += dmatg[(c << 6) + lane];
            vin += vmatg[(c << 6) + lane];
        }
        float inp = cv + vin;
        mem  = fmaf(mem - rst, beta, inp * omb);
        float mthr = fmaf(mem, inv, -bb);
        int s = mthr > 0.0f;
        mask = __ballot(s);
        if (lane == 0) bits[bitbase + (size_t)t * NHW] = mask;
    }
}

// ---------------------------------------------------------------
// Per-t spike counts from the packed bitmasks (no atomics anywhere)
// ---------------------------------------------------------------
__global__ __launch_bounds__(256) void count_kernel(const unsigned long long* __restrict__ bits,
                                                    int* __restrict__ cnt) {
    const int t = blockIdx.x;   // 0..49
    int sum = 0;
    for (int i = threadIdx.x; i < NB * NHW; i += 256) {
        int b  = i >> 10;
        int px = i & 1023;
        sum += __popcll(bits[((size_t)(b * NT + t) << 10) + px]);
    }
    __shared__ int sh[4];
#pragma unroll
    for (int off = 32; off > 0; off >>= 1) sum += __shfl_down(sum, off);
    if ((threadIdx.x & 63) == 0) sh[threadIdx.x >> 6] = sum;
    __syncthreads();
    if (threadIdx.x == 0) cnt[t] = sh[0] + sh[1] + sh[2] + sh[3];
}

// ---------------------------------------------------------------
// Unpack bitmasks -> fp32 spk_rec in (B, COUT, T, H, W) order
// ---------------------------------------------------------------
__global__ __launch_bounds__(256) void unpack_kernel(const unsigned long long* __restrict__ bits,
                                                     float* __restrict__ out) {
    const long long total4 = 13107200;  // 52,428,800 / 4
    const long long stride = (long long)gridDim.x * blockDim.x;
    for (long long i4 = (long long)blockIdx.x * 256 + threadIdx.x; i4 < total4; i4 += stride) {
        long long flat = i4 << 2;
        int hw = (int)(flat & 1023);
        long long r = flat >> 10;        // (b*64+o)*50 + t
        int t = (int)(r % 50);
        long long r2 = r / 50;           // b*64 + o
        int o = (int)(r2 & 63);
        int b = (int)(r2 >> 6);
        const unsigned long long* bq = bits + ((long long)(b * NT + t) << 10) + hw;
        float4 v;
        v.x = (float)((bq[0] >> o) & 1ull);
        v.y = (float)((bq[1] >> o) & 1ull);
        v.z = (float)((bq[2] >> o) & 1ull);
        v.w = (float)((bq[3] >> o) & 1ull);
        *(float4*)(out + flat) = v;
    }
}

// ---------------------------------------------------------------
// loss = 0.5 * sum(spk)/52428800 (spk^2 == spk), spread = max_t cnt[t]/1048576
// ---------------------------------------------------------------
__global__ __launch_bounds__(64) void finalize_kernel(const int* __restrict__ cnt,
                                                      float* __restrict__ out) {
    const int lane = threadIdx.x;
    int c = (lane < NT) ? cnt[lane] : 0;
    int tot = c, mx = c;
#pragma unroll
    for (int off = 32; off > 0; off >>= 1) {
        tot += __shfl_down(tot, off);
        mx = max(mx, __shfl_down(mx, off));
    }
    if (lane == 0) {
        out[52428800] = 0.5f * (float)tot / 52428800.0f;
        out[52428801] = (float)mx / 1048576.0f;
    }
}

extern "C" void kernel_launch(void* const* d_in, const int* in_sizes, int n_in,
                              void* d_out, int out_size, void* d_ws, size_t ws_size,
                              hipStream_t stream) {
    const float* x    = (const float*)d_in[0];
    const float* w    = (const float*)d_in[1];
    const float* v    = (const float*)d_in[2];
    const float* beta = (const float*)d_in[3];
    const float* b    = (const float*)d_in[4];
    // sigma (d_in[5]) only affects the backward pass — unused here.
    float* out = (float*)d_out;

    char* ws = (char*)d_ws;
    float* convo              = (float*)(ws);
    float* dmat               = (float*)(ws + 209715200);
    float* invn               = (float*)(ws + 209715200 + 16384);
    unsigned long long* bits  = (unsigned long long*)(ws + 209731840);
    int* cnt                  = (int*)(ws + 216285440);
    float* wT                 = (float*)(ws + 216285696);

    gram_kernel<<<64, 64, 0, stream>>>(w, dmat, invn);
    wtrans_kernel<<<108, 256, 0, stream>>>(w, wT);
    conv_kernel<<<dim3(8, NT, NB), 256, 0, stream>>>(x, wT, convo);
    scan_kernel<<<4096, 256, 0, stream>>>(convo, v, beta, b, dmat, invn, bits);
    count_kernel<<<NT, 256, 0, stream>>>(bits, cnt);
    unpack_kernel<<<4096, 256, 0, stream>>>(bits, out);
    finalize_kernel<<<1, 64, 0, stream>>>(cnt, out);
}